// Round 1
// baseline (1486.122 us; speedup 1.0000x reference)
//
#include <hip/hip_runtime.h>

#define NN   100000
#define EE   1600000
#define HIDF 128
#define OUTF 64
#define KSEL 32

static __device__ __forceinline__ unsigned int sortable_key(float f) {
    unsigned int u = __float_as_uint(f);
    return (u & 0x80000000u) ? ~u : (u | 0x80000000u);
}

// ---------------- degree histogram ----------------
__global__ __launch_bounds__(256) void hist_kernel(const int* __restrict__ src,
                                                   const int* __restrict__ dst,
                                                   int* __restrict__ cnt_out,
                                                   int* __restrict__ cnt_in, int e) {
    int i = blockIdx.x * 256 + threadIdx.x;
    if (i < e) {
        atomicAdd(&cnt_out[src[i]], 1);
        atomicAdd(&cnt_in[dst[i]], 1);
    }
}

// ---------------- prefix scan (3 kernels) ----------------
__global__ __launch_bounds__(256) void scan_block(const int* __restrict__ cnt,
                                                  int* __restrict__ incl,
                                                  int* __restrict__ bsums, int n) {
    __shared__ int s[256];
    int t = threadIdx.x;
    int i = blockIdx.x * 256 + t;
    int v = (i < n) ? cnt[i] : 0;
    s[t] = v;
    __syncthreads();
    for (int off = 1; off < 256; off <<= 1) {
        int x = (t >= off) ? s[t - off] : 0;
        __syncthreads();
        s[t] += x;
        __syncthreads();
    }
    if (i < n) incl[i] = s[t];
    if (t == 255) bsums[blockIdx.x] = s[255];
}

__global__ __launch_bounds__(512) void scan_sums(const int* __restrict__ bsums,
                                                 int* __restrict__ boff, int nb) {
    __shared__ int s[512];
    int t = threadIdx.x;
    int v = (t < nb) ? bsums[t] : 0;
    s[t] = v;
    __syncthreads();
    for (int off = 1; off < 512; off <<= 1) {
        int x = (t >= off) ? s[t - off] : 0;
        __syncthreads();
        s[t] += x;
        __syncthreads();
    }
    boff[t] = s[t] - v;  // exclusive
}

__global__ __launch_bounds__(256) void finalize_offsets(const int* __restrict__ incl,
                                                        const int* __restrict__ boff,
                                                        const int* __restrict__ cnt,
                                                        int* __restrict__ row_off,
                                                        int* __restrict__ cursor, int n) {
    int i = blockIdx.x * 256 + threadIdx.x;
    if (i < n) {
        int val = incl[i] + boff[i >> 8];
        row_off[i + 1] = val;
        cursor[i] = val - cnt[i];
        if (i == 0) row_off[0] = 0;
    }
}

__global__ __launch_bounds__(256) void deg_inv_kernel(const int* __restrict__ co,
                                                      const int* __restrict__ ci,
                                                      float* __restrict__ dvo,
                                                      float* __restrict__ dvi, int n) {
    int i = blockIdx.x * 256 + threadIdx.x;
    if (i < n) {
        dvo[i] = rsqrtf((float)max(co[i], 1));
        dvi[i] = rsqrtf((float)max(ci[i], 1));
    }
}

__global__ __launch_bounds__(256) void csr_fill(const int* __restrict__ src,
                                                const int* __restrict__ dst,
                                                int* __restrict__ cursor,
                                                int* __restrict__ csr, int e) {
    int i = blockIdx.x * 256 + threadIdx.x;
    if (i < e) {
        int d = dst[i];
        int pos = atomicAdd(&cursor[d], 1);
        csr[pos] = src[i];
    }
}

// ---------------- GEMM [n,128] x [128,128] + bias + ReLU -> dense ----------------
__global__ __launch_bounds__(256) void gemm_relu(const float* __restrict__ A,
                                                 const float* __restrict__ W,
                                                 const float* __restrict__ bias,
                                                 float* __restrict__ out, int n) {
    __shared__ float As[64][32];
    __shared__ float Ws[32][128];
    const int tid = threadIdx.x;
    const int rbase = blockIdx.x * 64;
    const int cc = tid & 31;          // cols 4*cc .. 4*cc+3
    const int r0 = (tid >> 5) * 8;    // 8 rows
    float acc[8][4];
#pragma unroll
    for (int i = 0; i < 8; ++i) { acc[i][0] = 0.f; acc[i][1] = 0.f; acc[i][2] = 0.f; acc[i][3] = 0.f; }

    for (int kc = 0; kc < 4; ++kc) {
        int lr = tid >> 3, c4 = (tid & 7) * 4;
#pragma unroll
        for (int p = 0; p < 2; ++p) {
            int row = lr + p * 32, gr = rbase + row;
            float4 v = make_float4(0.f, 0.f, 0.f, 0.f);
            if (gr < n) v = *(const float4*)(A + (size_t)gr * 128 + kc * 32 + c4);
            *(float4*)&As[row][c4] = v;
        }
        int wr = tid >> 5;
#pragma unroll
        for (int p = 0; p < 4; ++p) {
            int row = wr + p * 8;
            *(float4*)&Ws[row][cc * 4] = *(const float4*)(W + (size_t)(kc * 32 + row) * 128 + cc * 4);
        }
        __syncthreads();
#pragma unroll
        for (int k = 0; k < 32; k += 4) {
            float4 w0 = *(float4*)&Ws[k + 0][cc * 4];
            float4 w1 = *(float4*)&Ws[k + 1][cc * 4];
            float4 w2 = *(float4*)&Ws[k + 2][cc * 4];
            float4 w3 = *(float4*)&Ws[k + 3][cc * 4];
#pragma unroll
            for (int i = 0; i < 8; ++i) {
                float4 a = *(float4*)&As[r0 + i][k];
                acc[i][0] += a.x * w0.x + a.y * w1.x + a.z * w2.x + a.w * w3.x;
                acc[i][1] += a.x * w0.y + a.y * w1.y + a.z * w2.y + a.w * w3.y;
                acc[i][2] += a.x * w0.z + a.y * w1.z + a.z * w2.z + a.w * w3.z;
                acc[i][3] += a.x * w0.w + a.y * w1.w + a.z * w2.w + a.w * w3.w;
            }
        }
        __syncthreads();
    }
    float4 b4 = *(const float4*)(bias + cc * 4);
#pragma unroll
    for (int i = 0; i < 8; ++i) {
        int gr = rbase + r0 + i;
        if (gr < n) {
            float4 o = make_float4(fmaxf(acc[i][0] + b4.x, 0.f), fmaxf(acc[i][1] + b4.y, 0.f),
                                   fmaxf(acc[i][2] + b4.z, 0.f), fmaxf(acc[i][3] + b4.w, 0.f));
            *(float4*)(out + (size_t)gr * 128 + cc * 4) = o;
        }
    }
}

// ---------------- GEMM + bias + MaxK(top-32) -> sparse (vals scaled by deg_out^-1/2) ----------------
__global__ __launch_bounds__(256) void gemm_maxk(const float* __restrict__ A,
                                                 const float* __restrict__ W,
                                                 const float* __restrict__ bias,
                                                 const float* __restrict__ dvout,
                                                 float* __restrict__ svals,
                                                 unsigned char* __restrict__ sidx, int n) {
    __shared__ float As[64][32];
    __shared__ float Ws[32][128];
    __shared__ float G[64][128];
    const int tid = threadIdx.x;
    const int rbase = blockIdx.x * 64;
    const int cc = tid & 31;
    const int r0 = (tid >> 5) * 8;
    float acc[8][4];
#pragma unroll
    for (int i = 0; i < 8; ++i) { acc[i][0] = 0.f; acc[i][1] = 0.f; acc[i][2] = 0.f; acc[i][3] = 0.f; }

    for (int kc = 0; kc < 4; ++kc) {
        int lr = tid >> 3, c4 = (tid & 7) * 4;
#pragma unroll
        for (int p = 0; p < 2; ++p) {
            int row = lr + p * 32, gr = rbase + row;
            float4 v = make_float4(0.f, 0.f, 0.f, 0.f);
            if (gr < n) v = *(const float4*)(A + (size_t)gr * 128 + kc * 32 + c4);
            *(float4*)&As[row][c4] = v;
        }
        int wr = tid >> 5;
#pragma unroll
        for (int p = 0; p < 4; ++p) {
            int row = wr + p * 8;
            *(float4*)&Ws[row][cc * 4] = *(const float4*)(W + (size_t)(kc * 32 + row) * 128 + cc * 4);
        }
        __syncthreads();
#pragma unroll
        for (int k = 0; k < 32; k += 4) {
            float4 w0 = *(float4*)&Ws[k + 0][cc * 4];
            float4 w1 = *(float4*)&Ws[k + 1][cc * 4];
            float4 w2 = *(float4*)&Ws[k + 2][cc * 4];
            float4 w3 = *(float4*)&Ws[k + 3][cc * 4];
#pragma unroll
            for (int i = 0; i < 8; ++i) {
                float4 a = *(float4*)&As[r0 + i][k];
                acc[i][0] += a.x * w0.x + a.y * w1.x + a.z * w2.x + a.w * w3.x;
                acc[i][1] += a.x * w0.y + a.y * w1.y + a.z * w2.y + a.w * w3.y;
                acc[i][2] += a.x * w0.z + a.y * w1.z + a.z * w2.z + a.w * w3.z;
                acc[i][3] += a.x * w0.w + a.y * w1.w + a.z * w2.w + a.w * w3.w;
            }
        }
        __syncthreads();
    }
    {
        float4 b4 = *(const float4*)(bias + cc * 4);
#pragma unroll
        for (int i = 0; i < 8; ++i) {
            float4 o = make_float4(acc[i][0] + b4.x, acc[i][1] + b4.y,
                                   acc[i][2] + b4.z, acc[i][3] + b4.w);
            *(float4*)&G[r0 + i][cc * 4] = o;
        }
    }
    __syncthreads();

    const int lane = tid & 63;
    const int wv = tid >> 6;  // 0..3, handles rows wv*16 .. wv*16+15
    const unsigned long long lt = (1ull << lane) - 1ull;

    for (int rr = 0; rr < 16; ++rr) {
        int row = wv * 16 + rr;
        int node = rbase + row;
        if (node >= n) break;  // wave-uniform
        float v0 = G[row][lane];
        float v1 = G[row][lane + 64];
        unsigned int k0 = sortable_key(v0), k1 = sortable_key(v1);
        // radix binary search for the 32nd-largest key T (== pref at end)
        unsigned int pref = 0u;
        for (int bit = 31; bit >= 0; --bit) {
            unsigned int cand = pref | (1u << bit);
            unsigned long long b0 = __ballot(k0 >= cand);
            unsigned long long b1 = __ballot(k1 >= cand);
            if (__popcll(b0) + __popcll(b1) >= KSEL) pref = cand;
        }
        unsigned long long g0 = __ballot(k0 > pref), g1 = __ballot(k1 > pref);
        unsigned long long e0 = __ballot(k0 == pref), e1 = __ballot(k1 == pref);
        int m = __popcll(g0) + __popcll(g1);
        int need = KSEL - m;  // ties at T: take lowest feature indices first (JAX top_k)
        float ds = dvout[node];
        int slot = -1;
        if (k0 > pref) slot = __popcll(g0 & lt);
        else if (k0 == pref) { int r = __popcll(e0 & lt); if (r < need) slot = m + r; }
        if (slot >= 0) {
            svals[(size_t)node * 32 + slot] = v0 * ds;
            sidx[(size_t)node * 32 + slot] = (unsigned char)lane;
        }
        slot = -1;
        if (k1 > pref) slot = __popcll(g0) + __popcll(g1 & lt);
        else if (k1 == pref) { int r = __popcll(e0) + __popcll(e1 & lt); if (r < need) slot = m + r; }
        if (slot >= 0) {
            svals[(size_t)node * 32 + slot] = v1 * ds;
            sidx[(size_t)node * 32 + slot] = (unsigned char)(lane + 64);
        }
    }
}

// ---------------- CSR aggregation: one wave per dst node, LDS accumulator ----------------
__global__ __launch_bounds__(256) void agg_kernel(const float* __restrict__ svals,
                                                  const unsigned char* __restrict__ sidx,
                                                  const int* __restrict__ row_off,
                                                  const int* __restrict__ csr_src,
                                                  const float* __restrict__ dvin,
                                                  const float* __restrict__ bg,
                                                  float* __restrict__ out, int n) {
    __shared__ float acc[4][128];
    const int wv = threadIdx.x >> 6;
    const int lane = threadIdx.x & 63;
    const int node = blockIdx.x * 4 + wv;
    acc[wv][lane] = 0.f;
    acc[wv][lane + 64] = 0.f;
    if (node < n) {
        int s0 = row_off[node], s1 = row_off[node + 1];
        int sub = lane >> 5, j = lane & 31;
        for (int e = s0 + sub; e < s1; e += 2) {
            int s = csr_src[e];
            float v = svals[(size_t)s * 32 + j];
            int f = sidx[(size_t)s * 32 + j];
            atomicAdd(&acc[wv][f], v);
        }
    }
    __syncthreads();
    if (node < n) {
        float dv = dvin[node];
        out[(size_t)node * 128 + lane] = acc[wv][lane] * dv + bg[lane];
        out[(size_t)node * 128 + lane + 64] = acc[wv][lane + 64] * dv + bg[lane + 64];
    }
}

// ---------------- GEMM [n,128] x [128,64] + bias -> d_out ----------------
__global__ __launch_bounds__(256) void gemm_out64(const float* __restrict__ A,
                                                  const float* __restrict__ W,
                                                  const float* __restrict__ bias,
                                                  float* __restrict__ out, int n) {
    __shared__ float As[64][32];
    __shared__ float Ws[32][64];
    const int tid = threadIdx.x;
    const int rbase = blockIdx.x * 64;
    const int cc = tid & 15;          // cols 4*cc
    const int r0 = (tid >> 4) * 4;    // 4 rows
    float acc[4][4];
#pragma unroll
    for (int i = 0; i < 4; ++i) { acc[i][0] = 0.f; acc[i][1] = 0.f; acc[i][2] = 0.f; acc[i][3] = 0.f; }

    for (int kc = 0; kc < 4; ++kc) {
        int lr = tid >> 3, c4 = (tid & 7) * 4;
#pragma unroll
        for (int p = 0; p < 2; ++p) {
            int row = lr + p * 32, gr = rbase + row;
            float4 v = make_float4(0.f, 0.f, 0.f, 0.f);
            if (gr < n) v = *(const float4*)(A + (size_t)gr * 128 + kc * 32 + c4);
            *(float4*)&As[row][c4] = v;
        }
        int wr = tid >> 4;  // 0..15
#pragma unroll
        for (int p = 0; p < 2; ++p) {
            int row = wr + p * 16;
            *(float4*)&Ws[row][cc * 4] = *(const float4*)(W + (size_t)(kc * 32 + row) * 64 + cc * 4);
        }
        __syncthreads();
#pragma unroll
        for (int k = 0; k < 32; k += 4) {
            float4 w0 = *(float4*)&Ws[k + 0][cc * 4];
            float4 w1 = *(float4*)&Ws[k + 1][cc * 4];
            float4 w2 = *(float4*)&Ws[k + 2][cc * 4];
            float4 w3 = *(float4*)&Ws[k + 3][cc * 4];
#pragma unroll
            for (int i = 0; i < 4; ++i) {
                float4 a = *(float4*)&As[r0 + i][k];
                acc[i][0] += a.x * w0.x + a.y * w1.x + a.z * w2.x + a.w * w3.x;
                acc[i][1] += a.x * w0.y + a.y * w1.y + a.z * w2.y + a.w * w3.y;
                acc[i][2] += a.x * w0.z + a.y * w1.z + a.z * w2.z + a.w * w3.z;
                acc[i][3] += a.x * w0.w + a.y * w1.w + a.z * w2.w + a.w * w3.w;
            }
        }
        __syncthreads();
    }
    float4 b4 = *(const float4*)(bias + cc * 4);
#pragma unroll
    for (int i = 0; i < 4; ++i) {
        int gr = rbase + r0 + i;
        if (gr < n) {
            float4 o = make_float4(acc[i][0] + b4.x, acc[i][1] + b4.y,
                                   acc[i][2] + b4.z, acc[i][3] + b4.w);
            *(float4*)(out + (size_t)gr * 64 + cc * 4) = o;
        }
    }
}

extern "C" void kernel_launch(void* const* d_in, const int* in_sizes, int n_in,
                              void* d_out, int out_size, void* d_ws, size_t ws_size,
                              hipStream_t stream) {
    const float* x     = (const float*)d_in[0];
    const int*   src   = (const int*)d_in[1];
    const int*   dst   = (const int*)d_in[2];
    const float* W_in  = (const float*)d_in[3];
    const float* b_in  = (const float*)d_in[4];
    const float* W1    = (const float*)d_in[5];
    const float* b1    = (const float*)d_in[6];
    const float* bg1   = (const float*)d_in[7];
    const float* W2    = (const float*)d_in[8];
    const float* b2    = (const float*)d_in[9];
    const float* bg2   = (const float*)d_in[10];
    const float* W_out = (const float*)d_in[11];
    const float* b_out = (const float*)d_in[12];
    float* out = (float*)d_out;

    char* p = (char*)d_ws;
    auto carve = [&](size_t bytes) {
        char* r = p;
        p += (bytes + 255) & ~(size_t)255;
        return r;
    };
    int*   cnt_out = (int*)carve((size_t)NN * 4);
    int*   cnt_in  = (int*)carve((size_t)NN * 4);
    float* dvout   = (float*)carve((size_t)NN * 4);
    float* dvin    = (float*)carve((size_t)NN * 4);
    int*   incl    = (int*)carve((size_t)NN * 4);
    int*   bsums   = (int*)carve(512 * 4);
    int*   boff    = (int*)carve(512 * 4);
    int*   row_off = (int*)carve((size_t)(NN + 1) * 4);
    int*   cursor  = (int*)carve((size_t)NN * 4);
    int*   csr_src = (int*)carve((size_t)EE * 4);
    float* hbuf    = (float*)carve((size_t)NN * HIDF * 4);
    float* svals   = (float*)carve((size_t)NN * KSEL * 4);
    unsigned char* sidx = (unsigned char*)carve((size_t)NN * KSEL);

    const int gN   = (NN + 255) / 256;   // 391
    const int gE   = (EE + 255) / 256;   // 6250
    const int gT   = (NN + 63) / 64;     // 1563 row tiles
    const int gAgg = (NN + 3) / 4;       // 25000

    hipMemsetAsync(cnt_out, 0, (size_t)NN * 4, stream);
    hipMemsetAsync(cnt_in, 0, (size_t)NN * 4, stream);
    hist_kernel<<<gE, 256, 0, stream>>>(src, dst, cnt_out, cnt_in, EE);
    scan_block<<<gN, 256, 0, stream>>>(cnt_in, incl, bsums, NN);
    scan_sums<<<1, 512, 0, stream>>>(bsums, boff, gN);
    finalize_offsets<<<gN, 256, 0, stream>>>(incl, boff, cnt_in, row_off, cursor, NN);
    deg_inv_kernel<<<gN, 256, 0, stream>>>(cnt_out, cnt_in, dvout, dvin, NN);
    csr_fill<<<gE, 256, 0, stream>>>(src, dst, cursor, csr_src, EE);

    gemm_relu<<<gT, 256, 0, stream>>>(x, W_in, b_in, hbuf, NN);

    gemm_maxk<<<gT, 256, 0, stream>>>(hbuf, W1, b1, dvout, svals, sidx, NN);
    agg_kernel<<<gAgg, 256, 0, stream>>>(svals, sidx, row_off, csr_src, dvin, bg1, hbuf, NN);

    gemm_maxk<<<gT, 256, 0, stream>>>(hbuf, W2, b2, dvout, svals, sidx, NN);
    agg_kernel<<<gAgg, 256, 0, stream>>>(svals, sidx, row_off, csr_src, dvin, bg2, hbuf, NN);

    gemm_out64<<<gT, 256, 0, stream>>>(hbuf, W_out, b_out, out, NN);
}